// Round 3
// baseline (1618.037 us; speedup 1.0000x reference)
//
#include <hip/hip_runtime.h>
#include <hip/hip_bf16.h>
#include <math.h>

#define DI __device__ __forceinline__

typedef short bf16x8 __attribute__((ext_vector_type(8)));
typedef float f32x4 __attribute__((ext_vector_type(4)));
typedef unsigned short u16;

DI u16 f2bf(float f){
  unsigned u = __float_as_uint(f);
  unsigned r = (u + 0x7FFFu + ((u>>16)&1u)) >> 16;
  return (u16)r;
}
DI float bf2f(u16 h){ return __uint_as_float(((unsigned)h)<<16); }
DI unsigned pack2(float a, float b){ return (unsigned)f2bf(a) | ((unsigned)f2bf(b)<<16); }
DI float gelu_exact(float v){ return 0.5f*v*(1.0f + erff(v*0.70710678118654752f)); }

DI void gload_lds16(const void* g, const void* l){
  __builtin_amdgcn_global_load_lds((const __attribute__((address_space(1))) void*)g,
                                   (__attribute__((address_space(3))) void*)(void*)l, 16, 0, 0);
}

// ---------------- K0: weight prep (fp32 -> bf16, padded rows zeroed) ---------
__global__ __launch_bounds__(256) void k0_prep(const float* __restrict__ qkvw,
    const float* __restrict__ pw, const float* __restrict__ w1, const float* __restrict__ w2,
    u16* __restrict__ wq, u16* __restrict__ wp, u16* __restrict__ w1b, u16* __restrict__ w2b){
  int i = blockIdx.x*256 + threadIdx.x;
  if (i < 122880){                       // wq: 640x192 (576 valid)
    int r = i/192;
    u16 v = 0;
    if (r < 576) v = f2bf(qkvw[i]);
    wq[i] = v;
  } else if (i < 172032){                // wp: 256x192 (192 valid)
    int j = i-122880; int r = j/192;
    u16 v = 0;
    if (r < 192) v = f2bf(pw[j]);
    wp[j] = v;
  } else if (i < 319488){                // w1: 768x192 exact
    int j = i-172032; w1b[j] = f2bf(w1[j]);
  } else if (i < 516096){                // w2: 256x768 (192 valid)
    int j = i-319488; int r = j/768;
    u16 v = 0;
    if (r < 192) v = f2bf(w2[j]);
    w2b[j] = v;
  }
}

// ---------------- K1: bn1 + window-permute -> win_t[tok][192] bf16 ----------
// win[n][c'][i][jj] = h[b][c][hb*8+jj][wcol], c'=(wcol&7)*24+(c>>3), i=c&7
// token t = i*8+jj ; 4 images per slice (b in [0,4))
__global__ __launch_bounds__(512) void k1_part(const float* __restrict__ x,
    const float* __restrict__ g1, const float* __restrict__ b1,
    const float* __restrict__ m1, const float* __restrict__ v1,
    u16* __restrict__ win_t){
  __shared__ u16 so[4*64*200];           // [wig*64+t][200], 102400 B
  int tid = threadIdx.x;
  int bx = blockIdx.x;
  int wg = bx & 3, hb = (bx>>2)&15, b = bx>>6;
#pragma unroll
  for (int i=0;i<24;i++){
    int lin = i*512 + tid;
    int w4 = lin & 7;
    int rowid = lin >> 3;                // 0..1535
    int c = rowid >> 3, jj = rowid & 7;
    float sc = g1[c]*rsqrtf(v1[c]+1e-5f);
    float sh = b1[c] - m1[c]*sc;
    float4 xv = *(const float4*)(x + (((size_t)(b*192 + c)*128 + hb*8 + jj)*128 + wg*32 + w4*4));
    int cg = c>>3, ci = c&7;
    int t = ci*8 + jj;
    float vv[4] = {xv.x, xv.y, xv.z, xv.w};
#pragma unroll
    for (int k=0;k<4;k++){
      int w = w4*4 + k;
      int wig = w>>3, q = w&7;
      so[(wig*64 + t)*200 + q*24 + cg] = f2bf(vv[k]*sc + sh);
    }
  }
  __syncthreads();
  int rowi = tid>>1, half = tid&1;
  size_t tok0 = ((size_t)((b*16+hb)*16 + wg*4))*64;
  u16* dst = win_t + (tok0 + rowi)*192 + half*96;
  const u16* src = so + rowi*200 + half*96;
#pragma unroll
  for (int ch=0; ch<12; ch++)
    *(uint4*)(dst + ch*8) = *(const uint4*)(src + ch*8);
}

// ---------------- GEMM template: C[m][n] = A[m][:]*B[n][:]^T ----------------
// A[M][K] row-major bf16 (weights, padded rows), B[N][K] row-major bf16 (tokens)
// 128x128 tile, BK=32, 4 waves, global_load_lds w16, chunk-XOR swizzle
template<int EPI>
__global__ __launch_bounds__(256) void gemm_k(
    const u16* __restrict__ A, const u16* __restrict__ B,
    const float* __restrict__ bias, const float* __restrict__ x2,
    u16* __restrict__ outA, u16* __restrict__ outB, float* __restrict__ outF,
    int K, int Mtiles, int Mvalid, size_t Nstr)
{
  __shared__ u16 As[128*32];
  __shared__ u16 Bs[128*32];
  int tid = threadIdx.x;
  int wid = tid>>6, lane = tid&63;
  int lm = lane&15, g = lane>>4;
  int bx = blockIdx.x;
  int mt = bx % Mtiles;
  size_t n0 = (size_t)(bx / Mtiles) * 128;
  int m0 = mt*128;
  int wm = wid>>1, wn = wid&1;

  f32x4 acc[4][4];
#pragma unroll
  for (int i=0;i<4;i++)
#pragma unroll
    for (int j=0;j<4;j++) acc[i][j] = (f32x4){0.f,0.f,0.f,0.f};

  int nK = K >> 5;
  for (int kt=0; kt<nK; kt++){
    int kk = kt<<5;
#pragma unroll
    for (int s=0;s<2;s++){
      int seg = s*256 + tid;
      int row = seg>>2, ch = seg&3;
      int chs = ch ^ (row&3);
      gload_lds16(A + (size_t)(m0+row)*K + kk + chs*8, (const char*)As + (s*256 + wid*64)*16);
      gload_lds16(B + (n0+(size_t)row)*K + kk + chs*8, (const char*)Bs + (s*256 + wid*64)*16);
    }
    asm volatile("s_waitcnt vmcnt(0)" ::: "memory");
    __syncthreads();
    bf16x8 af[4], bfr[4];
#pragma unroll
    for (int i=0;i<4;i++){
      int row = wm*64 + i*16 + lm;
      af[i]  = *(const bf16x8*)&As[row*32 + ((g ^ (row&3))<<3)];
      int rb  = wn*64 + i*16 + lm;
      bfr[i] = *(const bf16x8*)&Bs[rb*32 + ((g ^ (rb&3))<<3)];
    }
#pragma unroll
    for (int i=0;i<4;i++)
#pragma unroll
      for (int j=0;j<4;j++)
        acc[i][j] = __builtin_amdgcn_mfma_f32_16x16x32_bf16(af[i], bfr[j], acc[i][j], 0,0,0);
    __syncthreads();
  }

  int baseM = m0 + wm*64;
  size_t nbase = n0 + wn*64;

  if (EPI == 0){ // qkv: m<384 -> qk_t[tok][384] packed ; m>=384 -> v[192][Nstr]
    if (m0 < 384){
#pragma unroll
      for (int i=0;i<4;i++){
        int mcol = baseM + i*16 + 4*g;
        float b0=bias[mcol], b1_=bias[mcol+1], b2_=bias[mcol+2], b3_=bias[mcol+3];
#pragma unroll
        for (int j=0;j<4;j++){
          size_t tok = nbase + j*16 + lm;
          f32x4 v = acc[i][j];
          uint2 w; w.x = pack2(v[0]+b0, v[1]+b1_); w.y = pack2(v[2]+b2_, v[3]+b3_);
          *(uint2*)(outA + tok*384 + mcol) = w;
        }
      }
    } else {
#pragma unroll
      for (int i=0;i<4;i++)
#pragma unroll
        for (int j=0;j<4;j++){
          f32x4 v = acc[i][j];
#pragma unroll
          for (int r=0;r<4;r++){
            int m = baseM + i*16 + 4*g + r;
            if (m < Mvalid){
              size_t tok = nbase + j*16 + lm;
              outB[(size_t)(m-384)*Nstr + tok] = f2bf(v[r] + bias[m]);
            }
          }
        }
    }
  }
  if (EPI == 1){ // proj -> a_win[m][Nstr]
#pragma unroll
    for (int i=0;i<4;i++)
#pragma unroll
      for (int j=0;j<4;j++){
        f32x4 v = acc[i][j];
#pragma unroll
        for (int r=0;r<4;r++){
          int m = baseM + i*16 + 4*g + r;
          if (m < Mvalid){
            size_t tok = nbase + j*16 + lm;
            outB[(size_t)m*Nstr + tok] = f2bf(v[r] + bias[m]);
          }
        }
      }
  }
  if (EPI == 2){ // mlp1 + gelu -> g_t[tok][768] packed
#pragma unroll
    for (int i=0;i<4;i++){
      int mcol = baseM + i*16 + 4*g;
      float b0=bias[mcol], b1_=bias[mcol+1], b2_=bias[mcol+2], b3_=bias[mcol+3];
#pragma unroll
      for (int j=0;j<4;j++){
        size_t tok = nbase + j*16 + lm;
        f32x4 v = acc[i][j];
        uint2 w;
        w.x = pack2(gelu_exact(v[0]+b0), gelu_exact(v[1]+b1_));
        w.y = pack2(gelu_exact(v[2]+b2_), gelu_exact(v[3]+b3_));
        *(uint2*)(outA + tok*768 + mcol) = w;
      }
    }
  }
  if (EPI == 3){ // mlp2 + bias + x2 -> out fp32 (image layout, 4-image slice)
#pragma unroll
    for (int i=0;i<4;i++)
#pragma unroll
      for (int j=0;j<4;j++){
        f32x4 v = acc[i][j];
#pragma unroll
        for (int r=0;r<4;r++){
          int m = baseM + i*16 + 4*g + r;
          if (m < Mvalid){
            size_t nn = nbase + j*16 + lm;
            size_t bimg = nn>>14; size_t p = nn & 16383;
            size_t off = (bimg*192 + m)*16384 + p;
            outF[off] = v[r] + bias[m] + x2[off];
          }
        }
      }
  }
}

// ---------------- K3: windowed attention, 1 block/window, wave = head -------
__global__ __launch_bounds__(192) void k3_attn(const u16* __restrict__ qkt,
    const u16* __restrict__ vb, u16* __restrict__ ot, size_t Nstr){
  __shared__ u16 lds[3*3*4096];          // per wave: Kt, Vt, QP(Q then P)
  int tid = threadIdx.x;
  int hd = tid>>6;
  int lane = tid&63;
  int lm = lane&15, g = lane>>4;
  size_t win = blockIdx.x;
  u16* Kt = lds + hd*3*4096;
  u16* Vt = Kt + 4096;
  u16* QP = Vt + 4096;
  size_t tokb = win*64;

#pragma unroll
  for (int it=0; it<8; it++){
    int seg = it*64 + lane;
    int row = seg>>3, c16 = seg&7;
    int cs = (c16 ^ (row&7))*8;
    gload_lds16(qkt + (tokb+row)*384 + 192 + hd*64 + cs, (const char*)Kt + it*1024);
    gload_lds16(qkt + (tokb+row)*384 +       hd*64 + cs, (const char*)QP + it*1024);
    gload_lds16(vb + (size_t)(hd*64+row)*Nstr + tokb + cs, (const char*)Vt + it*1024);
  }
  asm volatile("s_waitcnt vmcnt(0)" ::: "memory");

  bf16x8 ak[4][2];
#pragma unroll
  for (int mt2=0; mt2<4; mt2++)
#pragma unroll
    for (int kd=0; kd<2; kd++){
      int row = mt2*16 + lm;
      ak[mt2][kd] = *(const bf16x8*)&Kt[row*64 + (((kd*4+g) ^ (row&7))<<3)];
    }

  float rinv[4];
#pragma unroll
  for (int nt=0; nt<4; nt++){
    int rowq = nt*16 + lm;
    bf16x8 bq0 = *(const bf16x8*)&QP[rowq*64 + (((0+g) ^ (rowq&7))<<3)];
    bf16x8 bq1 = *(const bf16x8*)&QP[rowq*64 + (((4+g) ^ (rowq&7))<<3)];
    f32x4 sa[4];
#pragma unroll
    for (int mt2=0; mt2<4; mt2++){
      f32x4 z = (f32x4){0.f,0.f,0.f,0.f};
      z = __builtin_amdgcn_mfma_f32_16x16x32_bf16(ak[mt2][0], bq0, z, 0,0,0);
      z = __builtin_amdgcn_mfma_f32_16x16x32_bf16(ak[mt2][1], bq1, z, 0,0,0);
      sa[mt2] = z;
    }
    float mx = -1e30f;
#pragma unroll
    for (int mt2=0; mt2<4; mt2++)
#pragma unroll
      for (int r=0;r<4;r++) mx = fmaxf(mx, sa[mt2][r]);
    mx = fmaxf(mx, __shfl_xor(mx, 16));
    mx = fmaxf(mx, __shfl_xor(mx, 32));
    float sum = 0.f;
    float e[4][4];
#pragma unroll
    for (int mt2=0; mt2<4; mt2++)
#pragma unroll
      for (int r=0;r<4;r++){ float t = __expf(0.125f*(sa[mt2][r]-mx)); e[mt2][r] = t; sum += t; }
    sum += __shfl_xor(sum, 16);
    sum += __shfl_xor(sum, 32);
    rinv[nt] = 1.0f / sum;
    int n = nt*16 + lm;
#pragma unroll
    for (int mt2=0; mt2<4; mt2++)
#pragma unroll
      for (int pr=0; pr<2; pr++){
        int m = mt2*16 + 4*g + pr*2;
        *(unsigned*)&QP[n*64 + (((m>>3) ^ (n&7))<<3) + (m&7)] = pack2(e[mt2][pr*2], e[mt2][pr*2+1]);
      }
  }

  f32x4 oa[4][4];
#pragma unroll
  for (int i=0;i<4;i++)
#pragma unroll
    for (int j=0;j<4;j++) oa[i][j] = (f32x4){0.f,0.f,0.f,0.f};
  bf16x8 av[4][2];
#pragma unroll
  for (int dt=0; dt<4; dt++)
#pragma unroll
    for (int km=0; km<2; km++){
      int row = dt*16 + lm;
      av[dt][km] = *(const bf16x8*)&Vt[row*64 + (((km*4+g) ^ (row&7))<<3)];
    }
#pragma unroll
  for (int nt=0; nt<4; nt++){
    int rowp = nt*16 + lm;
    bf16x8 bp0 = *(const bf16x8*)&QP[rowp*64 + (((0+g) ^ (rowp&7))<<3)];
    bf16x8 bp1 = *(const bf16x8*)&QP[rowp*64 + (((4+g) ^ (rowp&7))<<3)];
#pragma unroll
    for (int dt=0; dt<4; dt++){
      oa[dt][nt] = __builtin_amdgcn_mfma_f32_16x16x32_bf16(av[dt][0], bp0, oa[dt][nt], 0,0,0);
      oa[dt][nt] = __builtin_amdgcn_mfma_f32_16x16x32_bf16(av[dt][1], bp1, oa[dt][nt], 0,0,0);
    }
  }
#pragma unroll
  for (int nt=0; nt<4; nt++){
    size_t tok = tokb + nt*16 + lm;
#pragma unroll
    for (int dt=0; dt<4; dt++){
      f32x4 v = oa[dt][nt];
      uint2 w;
      w.x = pack2(v[0]*rinv[nt], v[1]*rinv[nt]);
      w.y = pack2(v[2]*rinv[nt], v[3]*rinv[nt]);
      *(uint2*)(ot + tok*192 + hd*64 + dt*16 + 4*g) = w;
    }
  }
}

// ---------------- K5: unpartition + residual -> x2 fp32 (into d_out) -------
__global__ __launch_bounds__(512) void k5_unpart(const u16* __restrict__ aw,
    const float* __restrict__ x, float* __restrict__ x2, size_t Nstr){
  __shared__ u16 abuf[192*288];          // [c][jj*36 + w'] image layout, 110592 B
  int tid = threadIdx.x;
  int bx = blockIdx.x;
  int wg = bx&3, hb = (bx>>2)&15, b = bx>>6;
  size_t tok0 = ((size_t)((b*16+hb)*16 + wg*4))*64;
#pragma unroll
  for (int i=0;i<12;i++){
    int idx = i*512 + tid;
    int cp = idx>>5, l32 = idx&31;
    uint4 v = *(const uint4*)(aw + (size_t)cp*Nstr + tok0 + l32*8);
    int q = cp/24, cg = cp - q*24;
    int ci = l32&7, wig = l32>>3;
    int c = cg*8 + ci;
    const u16* pv = (const u16*)&v;
#pragma unroll
    for (int k=0;k<8;k++)
      abuf[c*288 + k*36 + wig*8 + q] = pv[k];
  }
  __syncthreads();
#pragma unroll
  for (int i=0;i<24;i++){
    int lin = i*512 + tid;
    int w4 = lin&7, rowid = lin>>3;
    int c = rowid>>3, jj = rowid&7;
    size_t xoff = ((size_t)(b*192 + c)*128 + hb*8 + jj)*128 + wg*32 + w4*4;
    float4 xv = *(const float4*)(x + xoff);
    float vv[4] = {xv.x, xv.y, xv.z, xv.w};
    float4 o;
    o.x = vv[0] + bf2f(abuf[c*288 + jj*36 + w4*4 + 0]);
    o.y = vv[1] + bf2f(abuf[c*288 + jj*36 + w4*4 + 1]);
    o.z = vv[2] + bf2f(abuf[c*288 + jj*36 + w4*4 + 2]);
    o.w = vv[3] + bf2f(abuf[c*288 + jj*36 + w4*4 + 3]);
    *(float4*)(x2 + xoff) = o;
  }
}

// ---------------- K5b: bn2 + transpose -> h2_t[tok][192] bf16 ---------------
__global__ __launch_bounds__(256) void k5b_t(const float* __restrict__ x2,
    const float* __restrict__ g2, const float* __restrict__ be2,
    const float* __restrict__ m2, const float* __restrict__ v2,
    u16* __restrict__ h2t){
  __shared__ u16 t[64*260];              // 33280 B
  int tid = threadIdx.x;
  int bx = blockIdx.x;
  int b = bx/192; int rem = bx - b*192; int cb = rem>>6; int pb = rem&63;
#pragma unroll
  for (int i=0;i<16;i++){
    int idx = i*256 + tid;
    int cr = idx>>6, p4 = idx&63;
    int c = cb*64 + cr;
    float sc = g2[c]*rsqrtf(v2[c]+1e-5f);
    float sh = be2[c] - m2[c]*sc;
    float4 v = *(const float4*)(x2 + ((size_t)(b*192+c)*16384 + pb*256 + p4*4));
    uint2 w; w.x = pack2(v.x*sc+sh, v.y*sc+sh); w.y = pack2(v.z*sc+sh, v.w*sc+sh);
    *(uint2*)&t[cr*260 + p4*4] = w;
  }
  __syncthreads();
  size_t tokg = (size_t)b*16384 + pb*256 + tid;
  u16* dst = h2t + tokg*192 + cb*64;
#pragma unroll
  for (int cc=0; cc<8; cc++){
    u16 tmp[8];
#pragma unroll
    for (int k=0;k<8;k++) tmp[k] = t[(cc*8+k)*260 + tid];
    *(uint4*)(dst + cc*8) = *(const uint4*)tmp;
  }
}

// ---------------- launch ----------------------------------------------------
extern "C" void kernel_launch(void* const* d_in, const int* in_sizes, int n_in,
                              void* d_out, int out_size, void* d_ws, size_t ws_size,
                              hipStream_t stream){
  const float* x   = (const float*)d_in[0];
  const float* g1  = (const float*)d_in[1];
  const float* be1 = (const float*)d_in[2];
  const float* mu1 = (const float*)d_in[3];
  const float* va1 = (const float*)d_in[4];
  const float* qkvw= (const float*)d_in[5];
  const float* qkvb= (const float*)d_in[6];
  const float* pw  = (const float*)d_in[7];
  const float* pb  = (const float*)d_in[8];
  const float* g2  = (const float*)d_in[9];
  const float* be2 = (const float*)d_in[10];
  const float* mu2 = (const float*)d_in[11];
  const float* va2 = (const float*)d_in[12];
  const float* w1  = (const float*)d_in[13];
  const float* b1  = (const float*)d_in[14];
  const float* w2  = (const float*)d_in[15];
  const float* b2  = (const float*)d_in[16];
  float* out = (float*)d_out;
  char* ws = (char*)d_ws;

  // 4 slices of 4 images each; x2 lives in d_out. Peak ws = 145 MB.
  //   [0,24M):   wint              |  [0,96M): gt (MLP phase)
  //   [24,48M):  vbuf              |
  //   [48,72M):  o_t               |
  //   [72,96M):  awin              |
  //   [96,144M): qkt (attn) / h2t (MLP)
  //   [144M,+1M): bf16 weights
  const size_t MB = 1048576;
  u16*  wint = (u16*) (ws + 0*MB);
  u16*  vbuf = (u16*) (ws + 24*MB);
  u16*  o_t  = (u16*) (ws + 48*MB);
  u16*  awin = (u16*) (ws + 72*MB);
  u16*  gt   = (u16*) (ws + 0*MB);
  u16*  qkt  = (u16*) (ws + 96*MB);
  u16*  h2t  = (u16*) (ws + 96*MB);
  u16*  wq   = (u16*) (ws + 144*MB);
  u16*  wp   = wq  + 640*192;
  u16*  w1b  = wp  + 256*192;
  u16*  w2b  = w1b + 768*192;
  const size_t needed = 144*MB + 1032192;
  if (ws_size < needed) return;          // diagnostic: clean fail instead of fault

  const size_t SLICE_TOK = 65536;        // 4 images * 16384 px
  const size_t SLICE_ELT = SLICE_TOK * 192;

  k0_prep<<<2016,256,0,stream>>>(qkvw, pw, w1, w2, wq, wp, w1b, w2b);

  for (int s=0; s<4; s++){
    const float* xs = x   + (size_t)s*SLICE_ELT;
    float*      x2s = out + (size_t)s*SLICE_ELT;
    k1_part<<<256,512,0,stream>>>(xs, g1, be1, mu1, va1, wint);
    gemm_k<0><<<512*5,256,0,stream>>>(wq, wint, qkvb, nullptr,
                                      qkt, vbuf, nullptr, 192, 5, 576, SLICE_TOK);
    k3_attn<<<1024,192,0,stream>>>(qkt, vbuf, o_t, SLICE_TOK);
    gemm_k<1><<<512*2,256,0,stream>>>(wp, o_t, pb, nullptr,
                                      nullptr, awin, nullptr, 192, 2, 192, SLICE_TOK);
    k5_unpart<<<256,512,0,stream>>>(awin, xs, x2s, SLICE_TOK);
  }

  for (int s=0; s<4; s++){
    float* x2s = out + (size_t)s*SLICE_ELT;
    k5b_t<<<768,256,0,stream>>>(x2s, g2, be2, mu2, va2, h2t);
    gemm_k<2><<<512*6,256,0,stream>>>(w1b, h2t, b1, nullptr,
                                      gt, nullptr, nullptr, 192, 6, 768, SLICE_TOK);
    gemm_k<3><<<512*2,256,0,stream>>>(w2b, gt, b2, x2s,
                                      nullptr, nullptr, x2s, 768, 2, 192, SLICE_TOK);
  }
}

// Round 5
// 1584.669 us; speedup vs baseline: 1.0211x; 1.0211x over previous
//
#include <hip/hip_runtime.h>
#include <hip/hip_bf16.h>
#include <math.h>

#define DI __device__ __forceinline__

typedef short bf16x8 __attribute__((ext_vector_type(8)));
typedef float f32x4 __attribute__((ext_vector_type(4)));
typedef unsigned short u16;

DI u16 f2bf(float f){
  unsigned u = __float_as_uint(f);
  unsigned r = (u + 0x7FFFu + ((u>>16)&1u)) >> 16;
  return (u16)r;
}
DI float bf2f(u16 h){ return __uint_as_float(((unsigned)h)<<16); }
DI unsigned pack2(float a, float b){ return (unsigned)f2bf(a) | ((unsigned)f2bf(b)<<16); }
DI float gelu_exact(float v){ return 0.5f*v*(1.0f + erff(v*0.70710678118654752f)); }

DI void gload_lds16(const void* g, const void* l){
  __builtin_amdgcn_global_load_lds((const __attribute__((address_space(1))) void*)g,
                                   (__attribute__((address_space(3))) void*)(void*)l, 16, 0, 0);
}

// ---------------- K0: weight prep (fp32 -> bf16, padded rows zeroed) ---------
__global__ __launch_bounds__(256) void k0_prep(const float* __restrict__ qkvw,
    const float* __restrict__ pw, const float* __restrict__ w1, const float* __restrict__ w2,
    u16* __restrict__ wq, u16* __restrict__ wp, u16* __restrict__ w1b, u16* __restrict__ w2b){
  int i = blockIdx.x*256 + threadIdx.x;
  if (i < 122880){                       // wq: 640x192 (576 valid)
    int r = i/192;
    u16 v = 0;
    if (r < 576) v = f2bf(qkvw[i]);
    wq[i] = v;
  } else if (i < 172032){                // wp: 256x192 (192 valid)
    int j = i-122880; int r = j/192;
    u16 v = 0;
    if (r < 192) v = f2bf(pw[j]);
    wp[j] = v;
  } else if (i < 319488){                // w1: 768x192 exact
    int j = i-172032; w1b[j] = f2bf(w1[j]);
  } else if (i < 516096){                // w2: 256x768 (192 valid)
    int j = i-319488; int r = j/768;
    u16 v = 0;
    if (r < 192) v = f2bf(w2[j]);
    w2b[j] = v;
  }
}

// ---------------- K1: bn1 + window-permute -> win_t[tok][192] bf16 ----------
// win[n][c'][i][jj] = h[b][c][hb*8+jj][wcol], c'=(wcol&7)*24+(c>>3), i=c&7
// token t = i*8+jj
__global__ __launch_bounds__(512) void k1_part(const float* __restrict__ x,
    const float* __restrict__ g1, const float* __restrict__ b1,
    const float* __restrict__ m1, const float* __restrict__ v1,
    u16* __restrict__ win_t){
  __shared__ u16 so[4*64*200];           // [wig*64+t][200], 102400 B
  int tid = threadIdx.x;
  int bx = blockIdx.x;
  int wg = bx & 3, hb = (bx>>2)&15, b = bx>>6;
#pragma unroll
  for (int i=0;i<24;i++){
    int lin = i*512 + tid;
    int w4 = lin & 7;
    int rowid = lin >> 3;                // 0..1535
    int c = rowid >> 3, jj = rowid & 7;
    float sc = g1[c]*rsqrtf(v1[c]+1e-5f);
    float sh = b1[c] - m1[c]*sc;
    float4 xv = *(const float4*)(x + (((size_t)(b*192 + c)*128 + hb*8 + jj)*128 + wg*32 + w4*4));
    int cg = c>>3, ci = c&7;
    int t = ci*8 + jj;
    float vv[4] = {xv.x, xv.y, xv.z, xv.w};
#pragma unroll
    for (int k=0;k<4;k++){
      int w = w4*4 + k;
      int wig = w>>3, q = w&7;
      so[(wig*64 + t)*200 + q*24 + cg] = f2bf(vv[k]*sc + sh);
    }
  }
  __syncthreads();
  int rowi = tid>>1, half = tid&1;
  size_t tok0 = ((size_t)((b*16+hb)*16 + wg*4))*64;
  u16* dst = win_t + (tok0 + rowi)*192 + half*96;
  const u16* src = so + rowi*200 + half*96;
#pragma unroll
  for (int ch=0; ch<12; ch++)
    *(uint4*)(dst + ch*8) = *(const uint4*)(src + ch*8);
}

// ---------------- GEMM template: C[m][n] = A[m][:]*B[n][:]^T ----------------
// A[M][K] row-major bf16 (weights, padded rows), B[N][K] row-major bf16 (tokens)
// 128x128 tile, BK=32, 4 waves, global_load_lds w16, chunk-XOR swizzle,
// XCD-chunked block swizzle (grid always divisible by 8).
template<int EPI>
__global__ __launch_bounds__(256) void gemm_k(
    const u16* __restrict__ A, const u16* __restrict__ B,
    const float* __restrict__ bias, const float* __restrict__ x2,
    u16* __restrict__ outA, u16* __restrict__ outB, float* __restrict__ outF,
    int K, int Mtiles, int Mvalid, size_t Nstr)
{
  __shared__ u16 As[128*32];
  __shared__ u16 Bs[128*32];
  int tid = threadIdx.x;
  int wid = tid>>6, lane = tid&63;
  int lm = lane&15, g = lane>>4;
  int nwg = gridDim.x;
  int chunk = nwg >> 3;
  int bid = blockIdx.x;
  int wgid = (bid & 7) * chunk + (bid >> 3);   // XCD-contiguous logical id
  int mt = wgid % Mtiles;
  size_t n0 = (size_t)(wgid / Mtiles) * 128;
  int m0 = mt*128;
  int wm = wid>>1, wn = wid&1;

  f32x4 acc[4][4];
#pragma unroll
  for (int i=0;i<4;i++)
#pragma unroll
    for (int j=0;j<4;j++) acc[i][j] = (f32x4){0.f,0.f,0.f,0.f};

  int nK = K >> 5;
  for (int kt=0; kt<nK; kt++){
    int kk = kt<<5;
#pragma unroll
    for (int s=0;s<2;s++){
      int seg = s*256 + tid;
      int row = seg>>2, ch = seg&3;
      int chs = ch ^ (row&3);
      gload_lds16(A + (size_t)(m0+row)*K + kk + chs*8, (const char*)As + (s*256 + wid*64)*16);
      gload_lds16(B + (n0+(size_t)row)*K + kk + chs*8, (const char*)Bs + (s*256 + wid*64)*16);
    }
    asm volatile("s_waitcnt vmcnt(0)" ::: "memory");
    __syncthreads();
    bf16x8 af[4], bfr[4];
#pragma unroll
    for (int i=0;i<4;i++){
      int row = wm*64 + i*16 + lm;
      af[i]  = *(const bf16x8*)&As[row*32 + ((g ^ (row&3))<<3)];
      int rb  = wn*64 + i*16 + lm;
      bfr[i] = *(const bf16x8*)&Bs[rb*32 + ((g ^ (rb&3))<<3)];
    }
#pragma unroll
    for (int i=0;i<4;i++)
#pragma unroll
      for (int j=0;j<4;j++)
        acc[i][j] = __builtin_amdgcn_mfma_f32_16x16x32_bf16(af[i], bfr[j], acc[i][j], 0,0,0);
    __syncthreads();
  }

  int baseM = m0 + wm*64;
  size_t nbase = n0 + wn*64;

  if (EPI == 0){ // qkv: m<384 -> qk_t[tok][384] packed ; m>=384 -> v[192][Nstr]
    if (m0 < 384){
#pragma unroll
      for (int i=0;i<4;i++){
        int mcol = baseM + i*16 + 4*g;
        float b0=bias[mcol], b1_=bias[mcol+1], b2_=bias[mcol+2], b3_=bias[mcol+3];
#pragma unroll
        for (int j=0;j<4;j++){
          size_t tok = nbase + j*16 + lm;
          f32x4 v = acc[i][j];
          uint2 w; w.x = pack2(v[0]+b0, v[1]+b1_); w.y = pack2(v[2]+b2_, v[3]+b3_);
          *(uint2*)(outA + tok*384 + mcol) = w;
        }
      }
    } else {
#pragma unroll
      for (int i=0;i<4;i++)
#pragma unroll
        for (int j=0;j<4;j++){
          f32x4 v = acc[i][j];
#pragma unroll
          for (int r=0;r<4;r++){
            int m = baseM + i*16 + 4*g + r;
            if (m < Mvalid){
              size_t tok = nbase + j*16 + lm;
              outB[(size_t)(m-384)*Nstr + tok] = f2bf(v[r] + bias[m]);
            }
          }
        }
    }
  }
  if (EPI == 1){ // proj -> a_win[m][Nstr]
#pragma unroll
    for (int i=0;i<4;i++)
#pragma unroll
      for (int j=0;j<4;j++){
        f32x4 v = acc[i][j];
#pragma unroll
        for (int r=0;r<4;r++){
          int m = baseM + i*16 + 4*g + r;
          if (m < Mvalid){
            size_t tok = nbase + j*16 + lm;
            outB[(size_t)m*Nstr + tok] = f2bf(v[r] + bias[m]);
          }
        }
      }
  }
  if (EPI == 2){ // mlp1 + gelu -> g_t[tok][768] packed
#pragma unroll
    for (int i=0;i<4;i++){
      int mcol = baseM + i*16 + 4*g;
      float b0=bias[mcol], b1_=bias[mcol+1], b2_=bias[mcol+2], b3_=bias[mcol+3];
#pragma unroll
      for (int j=0;j<4;j++){
        size_t tok = nbase + j*16 + lm;
        f32x4 v = acc[i][j];
        uint2 w;
        w.x = pack2(gelu_exact(v[0]+b0), gelu_exact(v[1]+b1_));
        w.y = pack2(gelu_exact(v[2]+b2_), gelu_exact(v[3]+b3_));
        *(uint2*)(outA + tok*768 + mcol) = w;
      }
    }
  }
  if (EPI == 3){ // mlp2 + bias + x2 -> out fp32 (image layout)
#pragma unroll
    for (int i=0;i<4;i++)
#pragma unroll
      for (int j=0;j<4;j++){
        f32x4 v = acc[i][j];
#pragma unroll
        for (int r=0;r<4;r++){
          int m = baseM + i*16 + 4*g + r;
          if (m < Mvalid){
            size_t nn = nbase + j*16 + lm;
            size_t bimg = nn>>14; size_t p = nn & 16383;
            size_t off = (bimg*192 + m)*16384 + p;
            outF[off] = v[r] + bias[m] + x2[off];
          }
        }
      }
  }
}

// ---------------- K3: windowed attention, 1 block/window, wave = head -------
__global__ __launch_bounds__(192) void k3_attn(const u16* __restrict__ qkt,
    const u16* __restrict__ vb, u16* __restrict__ ot, size_t Nstr){
  __shared__ u16 lds[3*3*4096];          // per wave: Kt, Vt, QP(Q then P)
  int tid = threadIdx.x;
  int hd = tid>>6;
  int lane = tid&63;
  int lm = lane&15, g = lane>>4;
  size_t win = blockIdx.x;
  u16* Kt = lds + hd*3*4096;
  u16* Vt = Kt + 4096;
  u16* QP = Vt + 4096;
  size_t tokb = win*64;

#pragma unroll
  for (int it=0; it<8; it++){
    int seg = it*64 + lane;
    int row = seg>>3, c16 = seg&7;
    int cs = (c16 ^ (row&7))*8;
    gload_lds16(qkt + (tokb+row)*384 + 192 + hd*64 + cs, (const char*)Kt + it*1024);
    gload_lds16(qkt + (tokb+row)*384 +       hd*64 + cs, (const char*)QP + it*1024);
    gload_lds16(vb + (size_t)(hd*64+row)*Nstr + tokb + cs, (const char*)Vt + it*1024);
  }
  asm volatile("s_waitcnt vmcnt(0)" ::: "memory");

  bf16x8 ak[4][2];
#pragma unroll
  for (int mt2=0; mt2<4; mt2++)
#pragma unroll
    for (int kd=0; kd<2; kd++){
      int row = mt2*16 + lm;
      ak[mt2][kd] = *(const bf16x8*)&Kt[row*64 + (((kd*4+g) ^ (row&7))<<3)];
    }

  float rinv[4];
#pragma unroll
  for (int nt=0; nt<4; nt++){
    int rowq = nt*16 + lm;
    bf16x8 bq0 = *(const bf16x8*)&QP[rowq*64 + (((0+g) ^ (rowq&7))<<3)];
    bf16x8 bq1 = *(const bf16x8*)&QP[rowq*64 + (((4+g) ^ (rowq&7))<<3)];
    f32x4 sa[4];
#pragma unroll
    for (int mt2=0; mt2<4; mt2++){
      f32x4 z = (f32x4){0.f,0.f,0.f,0.f};
      z = __builtin_amdgcn_mfma_f32_16x16x32_bf16(ak[mt2][0], bq0, z, 0,0,0);
      z = __builtin_amdgcn_mfma_f32_16x16x32_bf16(ak[mt2][1], bq1, z, 0,0,0);
      sa[mt2] = z;
    }
    float mx = -1e30f;
#pragma unroll
    for (int mt2=0; mt2<4; mt2++)
#pragma unroll
      for (int r=0;r<4;r++) mx = fmaxf(mx, sa[mt2][r]);
    mx = fmaxf(mx, __shfl_xor(mx, 16));
    mx = fmaxf(mx, __shfl_xor(mx, 32));
    float sum = 0.f;
    float e[4][4];
#pragma unroll
    for (int mt2=0; mt2<4; mt2++)
#pragma unroll
      for (int r=0;r<4;r++){ float t = __expf(0.125f*(sa[mt2][r]-mx)); e[mt2][r] = t; sum += t; }
    sum += __shfl_xor(sum, 16);
    sum += __shfl_xor(sum, 32);
    rinv[nt] = 1.0f / sum;
    int n = nt*16 + lm;
#pragma unroll
    for (int mt2=0; mt2<4; mt2++)
#pragma unroll
      for (int pr=0; pr<2; pr++){
        int m = mt2*16 + 4*g + pr*2;
        *(unsigned*)&QP[n*64 + (((m>>3) ^ (n&7))<<3) + (m&7)] = pack2(e[mt2][pr*2], e[mt2][pr*2+1]);
      }
  }

  f32x4 oa[4][4];
#pragma unroll
  for (int i=0;i<4;i++)
#pragma unroll
    for (int j=0;j<4;j++) oa[i][j] = (f32x4){0.f,0.f,0.f,0.f};
  bf16x8 av[4][2];
#pragma unroll
  for (int dt=0; dt<4; dt++)
#pragma unroll
    for (int km=0; km<2; km++){
      int row = dt*16 + lm;
      av[dt][km] = *(const bf16x8*)&Vt[row*64 + (((km*4+g) ^ (row&7))<<3)];
    }
#pragma unroll
  for (int nt=0; nt<4; nt++){
    int rowp = nt*16 + lm;
    bf16x8 bp0 = *(const bf16x8*)&QP[rowp*64 + (((0+g) ^ (rowp&7))<<3)];
    bf16x8 bp1 = *(const bf16x8*)&QP[rowp*64 + (((4+g) ^ (rowp&7))<<3)];
#pragma unroll
    for (int dt=0; dt<4; dt++){
      oa[dt][nt] = __builtin_amdgcn_mfma_f32_16x16x32_bf16(av[dt][0], bp0, oa[dt][nt], 0,0,0);
      oa[dt][nt] = __builtin_amdgcn_mfma_f32_16x16x32_bf16(av[dt][1], bp1, oa[dt][nt], 0,0,0);
    }
  }
#pragma unroll
  for (int nt=0; nt<4; nt++){
    size_t tok = tokb + nt*16 + lm;
#pragma unroll
    for (int dt=0; dt<4; dt++){
      f32x4 v = oa[dt][nt];
      uint2 w;
      w.x = pack2(v[0]*rinv[nt], v[1]*rinv[nt]);
      w.y = pack2(v[2]*rinv[nt], v[3]*rinv[nt]);
      *(uint2*)(ot + tok*192 + hd*64 + dt*16 + 4*g) = w;
    }
  }
}

// ------ K5: unpartition + residual -> x2 fp32 AND bn2+transpose -> h2t ------
__global__ __launch_bounds__(512) void k5_unpart(const u16* __restrict__ aw,
    const float* __restrict__ x,
    const float* __restrict__ g2, const float* __restrict__ be2,
    const float* __restrict__ m2, const float* __restrict__ v2,
    float* __restrict__ x2, u16* __restrict__ h2t, size_t Nstr){
  __shared__ u16 abuf[192*288];          // phase1: [c][jj*36+w'] ; phase2: [lt][192] swz
  int tid = threadIdx.x;
  int bx = blockIdx.x;
  int wg = bx&3, hb = (bx>>2)&15, b = bx>>6;
  size_t tok0 = ((size_t)((b*16+hb)*16 + wg*4))*64;
#pragma unroll
  for (int i=0;i<12;i++){
    int idx = i*512 + tid;
    int cp = idx>>5, l32 = idx&31;
    uint4 v = *(const uint4*)(aw + (size_t)cp*Nstr + tok0 + l32*8);
    int q = cp/24, cg = cp - q*24;
    int ci = l32&7, wig = l32>>3;
    int c = cg*8 + ci;
    const u16* pv = (const u16*)&v;
#pragma unroll
    for (int k=0;k<8;k++)
      abuf[c*288 + k*36 + wig*8 + q] = pv[k];
  }
  __syncthreads();
  unsigned hreg[48];                     // bn2'd bf16, 4 per iter
#pragma unroll
  for (int i=0;i<24;i++){
    int lin = i*512 + tid;
    int w4 = lin&7, rowid = lin>>3;
    int c = rowid>>3, jj = rowid&7;
    float sc = g2[c]*rsqrtf(v2[c]+1e-5f);
    float sh = be2[c] - m2[c]*sc;
    size_t xoff = ((size_t)(b*192 + c)*128 + hb*8 + jj)*128 + wg*32 + w4*4;
    float4 xv = *(const float4*)(x + xoff);
    float4 o;
    o.x = xv.x + bf2f(abuf[c*288 + jj*36 + w4*4 + 0]);
    o.y = xv.y + bf2f(abuf[c*288 + jj*36 + w4*4 + 1]);
    o.z = xv.z + bf2f(abuf[c*288 + jj*36 + w4*4 + 2]);
    o.w = xv.w + bf2f(abuf[c*288 + jj*36 + w4*4 + 3]);
    *(float4*)(x2 + xoff) = o;
    hreg[i*2]   = pack2(o.x*sc+sh, o.y*sc+sh);
    hreg[i*2+1] = pack2(o.z*sc+sh, o.w*sc+sh);
  }
  __syncthreads();
#pragma unroll
  for (int i=0;i<24;i++){
    int lin = i*512 + tid;
    int w4 = lin&7, rowid = lin>>3;
    int c = rowid>>3, jj = rowid&7;
    const u16* hv = (const u16*)&hreg[i*2];
#pragma unroll
    for (int k=0;k<4;k++){
      int lt = jj*32 + w4*4 + k;
      abuf[lt*192 + (c ^ ((lt&7)<<3))] = hv[k];
    }
  }
  __syncthreads();
  int rowi = tid>>1, half = tid&1;
  int jj2 = rowi>>5, w2 = rowi&31;
  size_t tokg = (size_t)b*16384 + (size_t)(hb*8 + jj2)*128 + wg*32 + w2;
  u16* dst = h2t + tokg*192;
#pragma unroll
  for (int ch=0; ch<12; ch++){
    int cc = half*12 + ch;
    uint4 v = *(const uint4*)&abuf[rowi*192 + (((cc*16) ^ ((rowi&7)<<4))>>1)];
    *(uint4*)(dst + cc*8) = v;
  }
}

// ---------------- launch ----------------------------------------------------
extern "C" void kernel_launch(void* const* d_in, const int* in_sizes, int n_in,
                              void* d_out, int out_size, void* d_ws, size_t ws_size,
                              hipStream_t stream){
  const float* x   = (const float*)d_in[0];
  const float* g1  = (const float*)d_in[1];
  const float* be1 = (const float*)d_in[2];
  const float* mu1 = (const float*)d_in[3];
  const float* va1 = (const float*)d_in[4];
  const float* qkvw= (const float*)d_in[5];
  const float* qkvb= (const float*)d_in[6];
  const float* pw  = (const float*)d_in[7];
  const float* pb  = (const float*)d_in[8];
  const float* g2  = (const float*)d_in[9];
  const float* be2 = (const float*)d_in[10];
  const float* mu2 = (const float*)d_in[11];
  const float* va2 = (const float*)d_in[12];
  const float* w1  = (const float*)d_in[13];
  const float* b1  = (const float*)d_in[14];
  const float* w2  = (const float*)d_in[15];
  const float* b2  = (const float*)d_in[16];
  float* out = (float*)d_out;
  char* ws = (char*)d_ws;

  // Full-batch layout (ws_size known >= 768 MiB from harness fill), peak 481 MB:
  //   [0,96M):    wint -> o_t -> h2t
  //   [96,288M):  qkt                |  [96,192M): awin   |  [96,480M): gt
  //   [288,384M): vbuf
  //   [480M,+1M): bf16 weights
  // x2 lives in d_out (fp32 image layout).
  const size_t MB = 1048576;
  u16*  wint = (u16*) (ws + 0*MB);
  u16*  o_t  = (u16*) (ws + 0*MB);
  u16*  h2t  = (u16*) (ws + 0*MB);
  u16*  qkt  = (u16*) (ws + 96*MB);
  u16*  awin = (u16*) (ws + 96*MB);
  u16*  gt   = (u16*) (ws + 96*MB);
  u16*  vbuf = (u16*) (ws + 288*MB);
  u16*  wq   = (u16*) (ws + 480*MB);
  u16*  wp   = wq  + 640*192;
  u16*  w1b  = wp  + 256*192;
  u16*  w2b  = w1b + 768*192;
  const size_t needed = 480*MB + 1032192;
  if (ws_size < needed) return;          // diagnostic: clean fail instead of fault

  const size_t NTOK = 262144;            // 16 images * 16384 px

  k0_prep<<<2016,256,0,stream>>>(qkvw, pw, w1, w2, wq, wp, w1b, w2b);
  k1_part<<<1024,512,0,stream>>>(x, g1, be1, mu1, va1, wint);
  gemm_k<0><<<10240,256,0,stream>>>(wq, wint, qkvb, nullptr,
                                    qkt, vbuf, nullptr, 192, 5, 576, NTOK);
  k3_attn<<<4096,192,0,stream>>>(qkt, vbuf, o_t, NTOK);
  gemm_k<1><<<4096,256,0,stream>>>(wp, o_t, pb, nullptr,
                                   nullptr, awin, nullptr, 192, 2, 192, NTOK);
  k5_unpart<<<1024,512,0,stream>>>(awin, x, g2, be2, mu2, va2, out, h2t, NTOK);
  gemm_k<2><<<12288,256,0,stream>>>(w1b, h2t, b1, nullptr,
                                    gt, nullptr, nullptr, 192, 6, 768, NTOK);
  gemm_k<3><<<4096,256,0,stream>>>(w2b, gt, b2, out,
                                   nullptr, nullptr, out, 768, 2, 192, NTOK);
}